// Round 10
// baseline (243.341 us; speedup 1.0000x reference)
//
#include <hip/hip_runtime.h>

typedef __attribute__((ext_vector_type(8))) short bf16x8;
typedef __attribute__((ext_vector_type(4))) short bf16x4;
typedef __attribute__((ext_vector_type(4))) float f32x4;

constexpr int NB = 16;    // bases
constexpr int REFF = 9;   // relations

struct alignas(8) EPair { float v; int c; };   // c = src | (dst&31)<<20

__device__ __forceinline__ unsigned short f2bf(float f) {
  unsigned u = __float_as_uint(f);
  u += 0x7FFFu + ((u >> 16) & 1u);          // round-to-nearest-even
  return (unsigned short)(u >> 16);
}
__device__ __forceinline__ float bf2f(short s) {
  return __uint_as_float(((unsigned)(unsigned short)s) << 16);
}
__device__ __forceinline__ float bflo(unsigned u) {
  return __uint_as_float(u << 16);
}
__device__ __forceinline__ float bfhi(unsigned u) {
  return __uint_as_float(u & 0xFFFF0000u);
}
__device__ __forceinline__ unsigned pk2(float a, float b) {
  return (unsigned)f2bf(a) | ((unsigned)f2bf(b) << 16);
}

// ---------------- merged: histogram + prep (Xbf, W1p, W2p) ----------------
__device__ __forceinline__ unsigned short pack_w_one(const float* __restrict__ comps,
                                                     const float* __restrict__ bases,
                                                     int idx, int NTI, int NTOT) {
  int j = idx & 7;
  int lane = (idx >> 3) & 63;
  int ni = (idx >> 9) % NTI;
  int t = (idx >> 9) / NTI;        // r*8 + ks
  int ks = t & 7;
  int r = t >> 3;
  int k = ks * 32 + ((lane >> 4) << 3) + j;
  int n = ni * 16 + (lane & 15);
  float acc = 0.f;
#pragma unroll
  for (int b = 0; b < NB; ++b)
    acc += comps[r * NB + b] * bases[(size_t)b * 256 * NTOT + (size_t)k * NTOT + n];
  return f2bf(acc);
}

__global__ void hist_prep_kernel(const int* __restrict__ rows,
                                 int* __restrict__ deg1, int E,
                                 const float* __restrict__ features,
                                 unsigned short* __restrict__ Xbf,
                                 const float* __restrict__ comps1,
                                 const float* __restrict__ bases1,
                                 unsigned short* __restrict__ W1p,
                                 const float* __restrict__ comps2,
                                 const float* __restrict__ bases2,
                                 unsigned short* __restrict__ W2p, int N) {
  int idx = blockIdx.x * 256 + threadIdx.x;
  if (idx < E) atomicAdd(&deg1[rows[idx]], 1);
  const int n4 = N * 64;                 // float4 units of features
  const int PW1 = REFF * 8 * 16 * 512;   // 589824
  const int PW2 = REFF * 8 * 2 * 512;    // 73728
  if (idx < n4) {
    float4 f = reinterpret_cast<const float4*>(features)[idx];
    ushort4 o;
    o.x = f2bf(f.x); o.y = f2bf(f.y); o.z = f2bf(f.z); o.w = f2bf(f.w);
    reinterpret_cast<ushort4*>(Xbf)[idx] = o;
  } else if (idx < n4 + PW1) {
    int i = idx - n4;
    W1p[i] = pack_w_one(comps1, bases1, i, 16, 256);
  } else if (idx < n4 + PW1 + PW2) {
    int i = idx - n4 - PW1;
    W2p[i] = pack_w_one(comps2, bases2, i, 2, 32);
  }
}

// ---------------- scan over NR rows (R3-proven 3-pass) ----------------
__global__ void scan1_kernel(const int* __restrict__ deg, int* __restrict__ bsum,
                             int NR) {
  __shared__ int s[256];
  int t = threadIdx.x;
  int base = blockIdx.x * 1024 + t * 4;
  int acc = 0;
#pragma unroll
  for (int q = 0; q < 4; ++q)
    if (base + q < NR) acc += deg[base + q];
  s[t] = acc;
  __syncthreads();
  for (int off = 128; off > 0; off >>= 1) {
    if (t < off) s[t] += s[t + off];
    __syncthreads();
  }
  if (t == 0) bsum[blockIdx.x] = s[0];
}

__global__ void scan2_kernel(int* __restrict__ bsum, int* __restrict__ ptr,
                             int NT, int NR) {
  __shared__ int s[512];
  int t = threadIdx.x;
  int v = (t < NT) ? bsum[t] : 0;
  s[t] = v;
  __syncthreads();
  for (int off = 1; off < 512; off <<= 1) {
    int x = (t >= off) ? s[t - off] : 0;
    __syncthreads();
    s[t] += x;
    __syncthreads();
  }
  if (t < NT) bsum[t] = s[t] - v;          // exclusive
  if (t == NT - 1) ptr[NR] = s[t];
}

__global__ void scan3_kernel(const int* __restrict__ deg,
                             const int* __restrict__ bsum,
                             int* __restrict__ ptr, int NR) {
  __shared__ int s[256];
  int t = threadIdx.x;
  int base = blockIdx.x * 1024 + t * 4;
  int d[4];
#pragma unroll
  for (int q = 0; q < 4; ++q)
    d[q] = (base + q < NR) ? deg[base + q] : 0;
  int tsum = d[0] + d[1] + d[2] + d[3];
  s[t] = tsum;
  __syncthreads();
  for (int off = 1; off < 256; off <<= 1) {
    int x = (t >= off) ? s[t - off] : 0;
    __syncthreads();
    s[t] += x;
    __syncthreads();
  }
  int off0 = bsum[blockIdx.x] + s[t] - tsum;
#pragma unroll
  for (int q = 0; q < 4; ++q) {
    if (base + q < NR) ptr[base + q] = off0;
    off0 += d[q];
  }
}

__global__ void fill_kernel(const int* __restrict__ rows,
                            const int* __restrict__ cols,
                            const float* __restrict__ vals,
                            int* __restrict__ deg1, const int* __restrict__ ptr1,
                            EPair* __restrict__ pay1, int E, int N) {
  int e = blockIdx.x * 256 + threadIdx.x;
  if (e >= E) return;
  int g = rows[e];
  int dst = g % N;
  int o1 = atomicSub(&deg1[g], 1);
  EPair pv; pv.v = vals[e]; pv.c = cols[e] | ((dst & 31) << 20);
  pay1[ptr1[g] + o1 - 1] = pv;
}

// ---------------- fused layer 1 + layer-2 transform ----------------
// 512 threads / 8 waves; 32-row tile; wave w gathers rows [w*4, w*4+4) over a
// contiguous edge span with a 2-edge pipeline, register accumulation.
__global__ __launch_bounds__(512, 8)
void fused_l1(const EPair* __restrict__ pay1, const int* __restrict__ ptr1,
              const unsigned short* __restrict__ Xbf,
              const unsigned short* __restrict__ W1p,
              const float* __restrict__ bias1,
              const unsigned short* __restrict__ W2p,
              unsigned short* __restrict__ Y2, int N) {
  __shared__ unsigned short tile[32 * 256];   // 16 KB A-tile / out1 tile
  __shared__ unsigned short y2s[8][1024];     // 16 KB per-wave Y2 staging
  char* lds = reinterpret_cast<char*>(tile);
  const int tid = threadIdx.x;
  const int w = tid >> 6, lane = tid & 63;
  const int node0 = blockIdx.x * 32;

  f32x4 acc[2][2];
#pragma unroll
  for (int mi = 0; mi < 2; ++mi)
#pragma unroll
    for (int ni = 0; ni < 2; ++ni) acc[mi][ni] = (f32x4)(0.f);

  const int rowbase = node0 + w * 4;
  for (int r = 0; r < REFF; ++r) {
    // ---- gather: wave walks its 4-row edge span ----
    float ga[4][4];
#pragma unroll
    for (int k = 0; k < 4; ++k)
#pragma unroll
      for (int j = 0; j < 4; ++j) ga[k][j] = 0.f;
    {
      int g = r * N;
      int lo = rowbase < N ? rowbase : N;
      int hi = rowbase + 4 < N ? rowbase + 4 : N;
      int p = ptr1[g + lo];
      int pend = ptr1[g + hi];
      EPair e0, e1;
      if (p < pend) e0 = pay1[p];
      if (p + 1 < pend) e1 = pay1[p + 1];
      while (p < pend) {
        EPair c0 = e0, c1 = e1;
        bool has1 = (p + 1 < pend);
        if (p + 2 < pend) e0 = pay1[p + 2];
        if (p + 3 < pend) e1 = pay1[p + 3];
        bf16x4 x0 = *reinterpret_cast<const bf16x4*>(
            Xbf + (size_t)(c0.c & 0xFFFFF) * 256 + lane * 4);
        int k0 = __builtin_amdgcn_readfirstlane((c0.c >> 20) & 3);
        float v0 = c0.v;
        if (k0 == 0) { for (int j = 0; j < 4; ++j) ga[0][j] += v0 * bf2f(x0[j]); }
        else if (k0 == 1) { for (int j = 0; j < 4; ++j) ga[1][j] += v0 * bf2f(x0[j]); }
        else if (k0 == 2) { for (int j = 0; j < 4; ++j) ga[2][j] += v0 * bf2f(x0[j]); }
        else { for (int j = 0; j < 4; ++j) ga[3][j] += v0 * bf2f(x0[j]); }
        if (has1) {
          bf16x4 x1 = *reinterpret_cast<const bf16x4*>(
              Xbf + (size_t)(c1.c & 0xFFFFF) * 256 + lane * 4);
          int k1 = __builtin_amdgcn_readfirstlane((c1.c >> 20) & 3);
          float v1 = c1.v;
          if (k1 == 0) { for (int j = 0; j < 4; ++j) ga[0][j] += v1 * bf2f(x1[j]); }
          else if (k1 == 1) { for (int j = 0; j < 4; ++j) ga[1][j] += v1 * bf2f(x1[j]); }
          else if (k1 == 2) { for (int j = 0; j < 4; ++j) ga[2][j] += v1 * bf2f(x1[j]); }
          else { for (int j = 0; j < 4; ++j) ga[3][j] += v1 * bf2f(x1[j]); }
        }
        p += 2;
      }
    }
    // store 4 rows x 4 cols (8B per row) to swizzled bf16 tile
#pragma unroll
    for (int k = 0; k < 4; ++k) {
      int rr = w * 4 + k;
      uint2 o;
      o.x = pk2(ga[k][0], ga[k][1]);
      o.y = pk2(ga[k][2], ga[k][3]);
      int boff = (rr * 512 + lane * 8) ^ ((rr & 7) << 4);
      *reinterpret_cast<uint2*>(lds + boff) = o;
    }
    __syncthreads();
    // ---- MFMA phase ----
#pragma unroll 2
    for (int ks = 0; ks < 8; ++ks) {
      bf16x8 a[2];
#pragma unroll
      for (int mi = 0; mi < 2; ++mi) {
        int row = mi * 16 + (lane & 15);
        int boff = (row * 512 + ks * 64 + ((lane >> 4) << 4)) ^ ((row & 7) << 4);
        a[mi] = *reinterpret_cast<const bf16x8*>(lds + boff);
      }
#pragma unroll
      for (int ni = 0; ni < 2; ++ni) {
        int niG = w * 2 + ni;
        bf16x8 b = *reinterpret_cast<const bf16x8*>(
            W1p + (((size_t)(r * 8 + ks) * 16 + niG) << 9) + lane * 8);
#pragma unroll
        for (int mi = 0; mi < 2; ++mi)
          acc[mi][ni] = __builtin_amdgcn_mfma_f32_16x16x32_bf16(a[mi], b,
                                                               acc[mi][ni], 0, 0, 0);
      }
    }
    __syncthreads();
  }

  // epilogue: out1 tile = bf16(relu(acc + bias1)) -> LDS bf16 tile (same layout)
#pragma unroll
  for (int mi = 0; mi < 2; ++mi) {
#pragma unroll
    for (int ni = 0; ni < 2; ++ni) {
      int col = (w * 2 + ni) * 16 + (lane & 15);
      float bb = bias1[col];
#pragma unroll
      for (int reg = 0; reg < 4; ++reg) {
        int row = mi * 16 + ((lane >> 4) << 2) + reg;
        float v = fmaxf(acc[mi][ni][reg] + bb, 0.f);
        int b = (row * 512 + col * 2) ^ ((row & 7) << 4);
        *reinterpret_cast<unsigned short*>(lds + b) = f2bf(v);
      }
    }
  }
  __syncthreads();

  // layer-2 transform: wave w handles rp = w (wave 0 also rp=8); staged stores
  for (int rp = w; rp < REFF; rp += 8) {
    f32x4 a2[2][2];   // [mi][nj]
#pragma unroll
    for (int mi = 0; mi < 2; ++mi) {
      a2[mi][0] = (f32x4)(0.f);
      a2[mi][1] = (f32x4)(0.f);
    }
#pragma unroll
    for (int ks = 0; ks < 8; ++ks) {
      bf16x8 b0 = *reinterpret_cast<const bf16x8*>(
          W2p + (((size_t)(rp * 8 + ks) * 2 + 0) << 9) + lane * 8);
      bf16x8 b1 = *reinterpret_cast<const bf16x8*>(
          W2p + (((size_t)(rp * 8 + ks) * 2 + 1) << 9) + lane * 8);
#pragma unroll
      for (int mi = 0; mi < 2; ++mi) {
        int row = mi * 16 + (lane & 15);
        int boff = (row * 512 + ks * 64 + ((lane >> 4) << 4)) ^ ((row & 7) << 4);
        bf16x8 a = *reinterpret_cast<const bf16x8*>(lds + boff);
        a2[mi][0] = __builtin_amdgcn_mfma_f32_16x16x32_bf16(a, b0, a2[mi][0], 0, 0, 0);
        a2[mi][1] = __builtin_amdgcn_mfma_f32_16x16x32_bf16(a, b1, a2[mi][1], 0, 0, 0);
      }
    }
    // stage 32x32 bf16 into wave-private LDS, then full-line stores
    unsigned short* ys = y2s[w];
#pragma unroll
    for (int mi = 0; mi < 2; ++mi)
#pragma unroll
      for (int reg = 0; reg < 4; ++reg) {
        int row16 = mi * 16 + ((lane >> 4) << 2) + reg;
        ys[row16 * 32 + (lane & 15)] = f2bf(a2[mi][0][reg]);
        ys[row16 * 32 + 16 + (lane & 15)] = f2bf(a2[mi][1][reg]);
      }
    asm volatile("s_waitcnt lgkmcnt(0)" ::: "memory");
#pragma unroll
    for (int half = 0; half < 2; ++half) {
      int row = half * 16 + (lane >> 2);      // 0..31
      int chunk = lane & 3;                   // 16B chunk within 64B row slice
      uint4 v = *reinterpret_cast<const uint4*>(&ys[row * 32 + chunk * 8]);
      int grow = node0 + row;
      if (grow < N)
        *reinterpret_cast<uint4*>(Y2 + (size_t)grow * (REFF * 32) + rp * 32 + chunk * 8) = v;
    }
  }
}

// ---------------- layer 2 gather off CSR1: out[n] = bias2 + sum_r sum_e v*Y2[src][r] ----------------
__global__ __launch_bounds__(512, 8)
void gather_out_kernel(const EPair* __restrict__ pay1,
                       const int* __restrict__ ptr1,
                       const unsigned short* __restrict__ Y2,
                       const float* __restrict__ bias2,
                       float* __restrict__ out, int N) {
  int wv = threadIdx.x >> 6;
  int lane = threadIdx.x & 63;
  int qw = lane >> 4, c = lane & 15;
  int n = blockIdx.x * 8 + wv;
  if (n >= N) return;
  float ax = 0.f, ay = 0.f;
  for (int r = qw; r < REFF; r += 4) {
    int g = r * N + n;
    int p0 = ptr1[g], p1 = ptr1[g + 1];
    int p = p0;
    for (; p + 2 <= p1; p += 2) {
      EPair e0 = pay1[p];
      EPair e1 = pay1[p + 1];
      unsigned u0 = *reinterpret_cast<const unsigned*>(
          Y2 + (size_t)(e0.c & 0xFFFFF) * (REFF * 32) + r * 32 + c * 2);
      unsigned u1 = *reinterpret_cast<const unsigned*>(
          Y2 + (size_t)(e1.c & 0xFFFFF) * (REFF * 32) + r * 32 + c * 2);
      ax += e0.v * bflo(u0) + e1.v * bflo(u1);
      ay += e0.v * bfhi(u0) + e1.v * bfhi(u1);
    }
    if (p < p1) {
      EPair e0 = pay1[p];
      unsigned u0 = *reinterpret_cast<const unsigned*>(
          Y2 + (size_t)(e0.c & 0xFFFFF) * (REFF * 32) + r * 32 + c * 2);
      ax += e0.v * bflo(u0);
      ay += e0.v * bfhi(u0);
    }
  }
  ax += __shfl_xor(ax, 16); ay += __shfl_xor(ay, 16);
  ax += __shfl_xor(ax, 32); ay += __shfl_xor(ay, 32);
  if (lane < 16) {
    float2 o;
    o.x = ax + bias2[c * 2];
    o.y = ay + bias2[c * 2 + 1];
    reinterpret_cast<float2*>(out)[(size_t)n * 16 + c] = o;
  }
}

extern "C" void kernel_launch(void* const* d_in, const int* in_sizes, int n_in,
                              void* d_out, int out_size, void* d_ws, size_t ws_size,
                              hipStream_t stream) {
  const float* features = (const float*)d_in[0];
  const float* ver_vals = (const float*)d_in[1];
  const float* comps1   = (const float*)d_in[2];
  const float* bases1   = (const float*)d_in[3];
  const float* comps2   = (const float*)d_in[4];
  const float* bases2   = (const float*)d_in[5];
  const float* bias1    = (const float*)d_in[6];
  const float* bias2    = (const float*)d_in[7];
  const int* ver_rows   = (const int*)d_in[8];
  const int* ver_cols   = (const int*)d_in[9];

  const int N = in_sizes[0] / 256;   // 30000
  const int E = in_sizes[1];         // 500000
  const int NR = REFF * N;           // 270000
  const int NT = (NR + 1023) / 1024; // 264

  // ---- workspace layout (~40 MB; 64.1 MB proven-safe) ----
  char* p = (char*)d_ws;
  unsigned short* Xbf = (unsigned short*)p; p += (size_t)N * 256 * 2;        // 15.36 MB
  unsigned short* Y2  = (unsigned short*)p; p += (size_t)N * REFF * 32 * 2;  // 17.28 MB
  unsigned short* W1p = (unsigned short*)p; p += (size_t)REFF * 65536 * 2;   // 1.18 MB
  unsigned short* W2p = (unsigned short*)p; p += (size_t)REFF * 8192 * 2;    // 0.15 MB
  int* ptr1 = (int*)p;     p += (size_t)(NR + 4) * 4;
  EPair* pay1 = (EPair*)p; p += (size_t)E * 8;
  int* deg1 = (int*)p;     p += (size_t)NR * 4;
  int* bsum = (int*)p;     p += 512 * 4;

  // ---- CSR build + prep ----
  hipMemsetAsync(deg1, 0, (size_t)NR * 4, stream);
  const int prep_total = N * 64 + REFF * 8 * 16 * 512 + REFF * 8 * 2 * 512;
  const int hp_grid = ((prep_total > E ? prep_total : E) + 255) / 256;
  hist_prep_kernel<<<hp_grid, 256, 0, stream>>>(ver_rows, deg1, E,
                                                features, Xbf,
                                                comps1, bases1, W1p,
                                                comps2, bases2, W2p, N);
  scan1_kernel<<<NT, 256, 0, stream>>>(deg1, bsum, NR);
  scan2_kernel<<<1, 512, 0, stream>>>(bsum, ptr1, NT, NR);
  scan3_kernel<<<NT, 256, 0, stream>>>(deg1, bsum, ptr1, NR);
  fill_kernel<<<(E + 255) / 256, 256, 0, stream>>>(ver_rows, ver_cols, ver_vals,
                                                   deg1, ptr1, pay1, E, N);

  // ---- fused layer 1 + layer-2 transform ----
  fused_l1<<<(N + 31) / 32, 512, 0, stream>>>(pay1, ptr1, Xbf, W1p, bias1,
                                              W2p, Y2, N);
  // ---- layer 2 gather ----
  gather_out_kernel<<<(N + 7) / 8, 512, 0, stream>>>(pay1, ptr1, Y2, bias2,
                                                     (float*)d_out, N);
}

// Round 11
// 226.993 us; speedup vs baseline: 1.0720x; 1.0720x over previous
//
#include <hip/hip_runtime.h>

typedef __attribute__((ext_vector_type(8))) short bf16x8;
typedef __attribute__((ext_vector_type(4))) float f32x4;

constexpr int NB = 16;    // bases
constexpr int REFF = 9;   // relations

struct alignas(8) EPair { float v; int c; };   // c = src | (dst&31)<<20

__device__ __forceinline__ unsigned short f2bf(float f) {
  unsigned u = __float_as_uint(f);
  u += 0x7FFFu + ((u >> 16) & 1u);          // round-to-nearest-even
  return (unsigned short)(u >> 16);
}
__device__ __forceinline__ float bflo(unsigned u) {
  return __uint_as_float(u << 16);
}
__device__ __forceinline__ float bfhi(unsigned u) {
  return __uint_as_float(u & 0xFFFF0000u);
}

// ---------------- merged: histogram + prep (Xbf, W1p, W2p) ----------------
__device__ __forceinline__ unsigned short pack_w_one(const float* __restrict__ comps,
                                                     const float* __restrict__ bases,
                                                     int idx, int NTI, int NTOT) {
  int j = idx & 7;
  int lane = (idx >> 3) & 63;
  int ni = (idx >> 9) % NTI;
  int t = (idx >> 9) / NTI;        // r*8 + ks
  int ks = t & 7;
  int r = t >> 3;
  int k = ks * 32 + ((lane >> 4) << 3) + j;
  int n = ni * 16 + (lane & 15);
  float acc = 0.f;
#pragma unroll
  for (int b = 0; b < NB; ++b)
    acc += comps[r * NB + b] * bases[(size_t)b * 256 * NTOT + (size_t)k * NTOT + n];
  return f2bf(acc);
}

__global__ void hist_prep_kernel(const int* __restrict__ rows,
                                 int* __restrict__ deg1, int E,
                                 const float* __restrict__ features,
                                 unsigned short* __restrict__ Xbf,
                                 const float* __restrict__ comps1,
                                 const float* __restrict__ bases1,
                                 unsigned short* __restrict__ W1p,
                                 const float* __restrict__ comps2,
                                 const float* __restrict__ bases2,
                                 unsigned short* __restrict__ W2p, int N) {
  int idx = blockIdx.x * 256 + threadIdx.x;
  if (idx < E) atomicAdd(&deg1[rows[idx]], 1);
  const int n4 = N * 64;                 // float4 units of features
  const int PW1 = REFF * 8 * 16 * 512;   // 589824
  const int PW2 = REFF * 8 * 2 * 512;    // 73728
  if (idx < n4) {
    float4 f = reinterpret_cast<const float4*>(features)[idx];
    ushort4 o;
    o.x = f2bf(f.x); o.y = f2bf(f.y); o.z = f2bf(f.z); o.w = f2bf(f.w);
    reinterpret_cast<ushort4*>(Xbf)[idx] = o;
  } else if (idx < n4 + PW1) {
    int i = idx - n4;
    W1p[i] = pack_w_one(comps1, bases1, i, 16, 256);
  } else if (idx < n4 + PW1 + PW2) {
    int i = idx - n4 - PW1;
    W2p[i] = pack_w_one(comps2, bases2, i, 2, 32);
  }
}

// ---------------- scan over NR rows (R3-proven 3-pass) ----------------
__global__ void scan1_kernel(const int* __restrict__ deg, int* __restrict__ bsum,
                             int NR) {
  __shared__ int s[256];
  int t = threadIdx.x;
  int base = blockIdx.x * 1024 + t * 4;
  int acc = 0;
#pragma unroll
  for (int q = 0; q < 4; ++q)
    if (base + q < NR) acc += deg[base + q];
  s[t] = acc;
  __syncthreads();
  for (int off = 128; off > 0; off >>= 1) {
    if (t < off) s[t] += s[t + off];
    __syncthreads();
  }
  if (t == 0) bsum[blockIdx.x] = s[0];
}

__global__ void scan2_kernel(int* __restrict__ bsum, int* __restrict__ ptr,
                             int NT, int NR) {
  __shared__ int s[512];
  int t = threadIdx.x;
  int v = (t < NT) ? bsum[t] : 0;
  s[t] = v;
  __syncthreads();
  for (int off = 1; off < 512; off <<= 1) {
    int x = (t >= off) ? s[t - off] : 0;
    __syncthreads();
    s[t] += x;
    __syncthreads();
  }
  if (t < NT) bsum[t] = s[t] - v;          // exclusive
  if (t == NT - 1) ptr[NR] = s[t];
}

__global__ void scan3_kernel(const int* __restrict__ deg,
                             const int* __restrict__ bsum,
                             int* __restrict__ ptr, int NR) {
  __shared__ int s[256];
  int t = threadIdx.x;
  int base = blockIdx.x * 1024 + t * 4;
  int d[4];
#pragma unroll
  for (int q = 0; q < 4; ++q)
    d[q] = (base + q < NR) ? deg[base + q] : 0;
  int tsum = d[0] + d[1] + d[2] + d[3];
  s[t] = tsum;
  __syncthreads();
  for (int off = 1; off < 256; off <<= 1) {
    int x = (t >= off) ? s[t - off] : 0;
    __syncthreads();
    s[t] += x;
    __syncthreads();
  }
  int off0 = bsum[blockIdx.x] + s[t] - tsum;
#pragma unroll
  for (int q = 0; q < 4; ++q) {
    if (base + q < NR) ptr[base + q] = off0;
    off0 += d[q];
  }
}

__global__ void fill_kernel(const int* __restrict__ rows,
                            const int* __restrict__ cols,
                            const float* __restrict__ vals,
                            int* __restrict__ deg1, const int* __restrict__ ptr1,
                            EPair* __restrict__ pay1, int E, int N) {
  int e = blockIdx.x * 256 + threadIdx.x;
  if (e >= E) return;
  int g = rows[e];
  int dst = g % N;
  int o1 = atomicSub(&deg1[g], 1);
  EPair pv; pv.v = vals[e]; pv.c = cols[e] | ((dst & 31) << 20);
  pay1[ptr1[g] + o1 - 1] = pv;
}

// ---------------- fused layer 1 (MFMA-aggregation) + layer-2 transform ----------------
// 512 threads / 8 waves; 32-node tile. Per relation: edges in chunks of 32;
// stage Xt[256 n][32 k] transposed + Mt[32 node][32 k] coeffs; aggT = Xt @ Mt via MFMA.
__global__ __launch_bounds__(512, 4)
void fused_l1(const EPair* __restrict__ pay1, const int* __restrict__ ptr1,
              const unsigned short* __restrict__ Xbf,
              const unsigned short* __restrict__ W1p,
              const float* __restrict__ bias1,
              const unsigned short* __restrict__ W2p,
              unsigned short* __restrict__ Y2, int N) {
  __shared__ char smem[34 * 1024];
  char* Xt   = smem;               // 16 KB: [256 n][32 k] bf16, k-groups swizzled
  char* Mt   = smem + 16 * 1024;   // 2 KB:  [32 node][32 k] bf16, swizzled
  char* tile = smem + 18 * 1024;   // 16 KB: [32 node][256 n] bf16 (W1 A-tile layout)
  const int tid = threadIdx.x;
  const int w = tid >> 6, lane = tid & 63;
  const int l15 = lane & 15, kg = lane >> 4;
  const int node0 = blockIdx.x * 32;
  const int nrows = (N - node0 < 32) ? (N - node0) : 32;

  // zero Xt once (stale finite data is fine later; initial LDS may be NaN-patterned)
  {
    uint4 z = make_uint4(0, 0, 0, 0);
    *reinterpret_cast<uint4*>(Xt + tid * 32) = z;
    *reinterpret_cast<uint4*>(Xt + tid * 32 + 16) = z;
  }
  __syncthreads();

  f32x4 acc[2][2];
#pragma unroll
  for (int mi = 0; mi < 2; ++mi)
#pragma unroll
    for (int ni = 0; ni < 2; ++ni) acc[mi][ni] = (f32x4)(0.f);

  // staging coords: thread t handles edge slot k = t&31, n-range [(t>>5)*16, +16)
  const int sk = tid & 31;
  const int sn0 = (tid >> 5) << 4;

  for (int r = 0; r < REFF; ++r) {
    int g = r * N + node0;
    int s0 = ptr1[g], s1 = ptr1[g + nrows];
    int nch = (s1 - s0 + 31) >> 5;

    f32x4 agg[2][2];
#pragma unroll
    for (int mi = 0; mi < 2; ++mi)
#pragma unroll
      for (int ni = 0; ni < 2; ++ni) agg[mi][ni] = (f32x4)(0.f);

    for (int c = 0; c < nch; ++c) {
      int e0 = s0 + c * 32;
      int rem = s1 - e0; if (rem > 32) rem = 32;
      // ---- stage Xt (all waves, independent loads) ----
      if (sk < rem) {
        int src = pay1[e0 + sk].c & 0xFFFFF;
        const unsigned short* xr = Xbf + (size_t)src * 256 + sn0;
        bf16x8 x0 = *reinterpret_cast<const bf16x8*>(xr);
        bf16x8 x1 = *reinterpret_cast<const bf16x8*>(xr + 8);
        int klo = sk & 7;
        int kgr = sk >> 3;
#pragma unroll
        for (int i = 0; i < 8; ++i) {
          int n = sn0 + i;
          int off = n * 64 + (((kgr ^ (n & 3)) << 3 | klo) << 1);
          *reinterpret_cast<unsigned short*>(Xt + off) = (unsigned short)x0[i];
        }
#pragma unroll
        for (int i = 0; i < 8; ++i) {
          int n = sn0 + 8 + i;
          int off = n * 64 + (((kgr ^ (n & 3)) << 3 | klo) << 1);
          *reinterpret_cast<unsigned short*>(Xt + off) = (unsigned short)x1[i];
        }
      }
      // ---- Mt: wave 0 zeros then populates (same-wave LDS ops are ordered) ----
      if (tid < 64) {
        uint4 z = make_uint4(0, 0, 0, 0);
        *reinterpret_cast<uint4*>(Mt + tid * 32) = z;
        *reinterpret_cast<uint4*>(Mt + tid * 32 + 16) = z;
        if (tid < rem) {
          EPair e = pay1[e0 + tid];
          int rr = (e.c >> 20) & 31;
          int off = rr * 64 + (((((tid >> 3) ^ (rr & 3)) << 3) | (tid & 7)) << 1);
          *reinterpret_cast<unsigned short*>(Mt + off) = f2bf(e.v);
        }
      }
      __syncthreads();
      // ---- aggT += Xt(32n-slice) @ Mt ----
      {
        int n_0 = w * 32 + l15;
        int n_1 = n_0 + 16;
        bf16x8 a0 = *reinterpret_cast<const bf16x8*>(
            Xt + n_0 * 64 + ((kg ^ (n_0 & 3)) << 4));
        bf16x8 a1 = *reinterpret_cast<const bf16x8*>(
            Xt + n_1 * 64 + ((kg ^ (n_1 & 3)) << 4));
        bf16x8 b0 = *reinterpret_cast<const bf16x8*>(
            Mt + l15 * 64 + ((kg ^ (l15 & 3)) << 4));
        bf16x8 b1 = *reinterpret_cast<const bf16x8*>(
            Mt + (l15 + 16) * 64 + ((kg ^ (l15 & 3)) << 4));
        agg[0][0] = __builtin_amdgcn_mfma_f32_16x16x32_bf16(a0, b0, agg[0][0], 0, 0, 0);
        agg[0][1] = __builtin_amdgcn_mfma_f32_16x16x32_bf16(a0, b1, agg[0][1], 0, 0, 0);
        agg[1][0] = __builtin_amdgcn_mfma_f32_16x16x32_bf16(a1, b0, agg[1][0], 0, 0, 0);
        agg[1][1] = __builtin_amdgcn_mfma_f32_16x16x32_bf16(a1, b1, agg[1][1], 0, 0, 0);
      }
      __syncthreads();
    }

    // ---- write aggT -> tile[node][n] (bf16, swizzled W1 A-layout) ----
#pragma unroll
    for (int mi = 0; mi < 2; ++mi)
#pragma unroll
      for (int ni = 0; ni < 2; ++ni)
#pragma unroll
        for (int reg = 0; reg < 4; ++reg) {
          int node = ni * 16 + l15;
          int n = w * 32 + mi * 16 + kg * 4 + reg;
          int byte = (node * 512 + n * 2) ^ ((node & 7) << 4);
          *reinterpret_cast<unsigned short*>(tile + byte) = f2bf(agg[mi][ni][reg]);
        }
    __syncthreads();
    // ---- acc += tile @ W1_r ----
#pragma unroll 2
    for (int ks = 0; ks < 8; ++ks) {
      bf16x8 a[2];
#pragma unroll
      for (int mi = 0; mi < 2; ++mi) {
        int row = mi * 16 + l15;
        int boff = (row * 512 + ks * 64 + (kg << 4)) ^ ((row & 7) << 4);
        a[mi] = *reinterpret_cast<const bf16x8*>(tile + boff);
      }
#pragma unroll
      for (int ni = 0; ni < 2; ++ni) {
        int niG = w * 2 + ni;
        bf16x8 b = *reinterpret_cast<const bf16x8*>(
            W1p + (((size_t)(r * 8 + ks) * 16 + niG) << 9) + lane * 8);
#pragma unroll
        for (int mi = 0; mi < 2; ++mi)
          acc[mi][ni] = __builtin_amdgcn_mfma_f32_16x16x32_bf16(a[mi], b,
                                                               acc[mi][ni], 0, 0, 0);
      }
    }
    __syncthreads();
  }

  // epilogue: out1 tile = bf16(relu(acc + bias1)) -> tile (same layout)
#pragma unroll
  for (int mi = 0; mi < 2; ++mi) {
#pragma unroll
    for (int ni = 0; ni < 2; ++ni) {
      int col = (w * 2 + ni) * 16 + l15;
      float bb = bias1[col];
#pragma unroll
      for (int reg = 0; reg < 4; ++reg) {
        int row = mi * 16 + (kg << 2) + reg;
        float v = fmaxf(acc[mi][ni][reg] + bb, 0.f);
        int b = (row * 512 + col * 2) ^ ((row & 7) << 4);
        *reinterpret_cast<unsigned short*>(tile + b) = f2bf(v);
      }
    }
  }
  __syncthreads();

  // layer-2 transform: wave w handles rp = w (wave 0 also rp=8); staged stores
  unsigned short* ys = reinterpret_cast<unsigned short*>(Xt) + w * 1024;  // 2 KB/wave
  for (int rp = w; rp < REFF; rp += 8) {
    f32x4 a2[2][2];   // [mi][nj]
#pragma unroll
    for (int mi = 0; mi < 2; ++mi) {
      a2[mi][0] = (f32x4)(0.f);
      a2[mi][1] = (f32x4)(0.f);
    }
#pragma unroll
    for (int ks = 0; ks < 8; ++ks) {
      bf16x8 b0 = *reinterpret_cast<const bf16x8*>(
          W2p + (((size_t)(rp * 8 + ks) * 2 + 0) << 9) + lane * 8);
      bf16x8 b1 = *reinterpret_cast<const bf16x8*>(
          W2p + (((size_t)(rp * 8 + ks) * 2 + 1) << 9) + lane * 8);
#pragma unroll
      for (int mi = 0; mi < 2; ++mi) {
        int row = mi * 16 + l15;
        int boff = (row * 512 + ks * 64 + (kg << 4)) ^ ((row & 7) << 4);
        bf16x8 a = *reinterpret_cast<const bf16x8*>(tile + boff);
        a2[mi][0] = __builtin_amdgcn_mfma_f32_16x16x32_bf16(a, b0, a2[mi][0], 0, 0, 0);
        a2[mi][1] = __builtin_amdgcn_mfma_f32_16x16x32_bf16(a, b1, a2[mi][1], 0, 0, 0);
      }
    }
    // stage 32x32 bf16 into wave-private LDS, then full-line stores
#pragma unroll
    for (int mi = 0; mi < 2; ++mi)
#pragma unroll
      for (int reg = 0; reg < 4; ++reg) {
        int row16 = mi * 16 + (kg << 2) + reg;
        ys[row16 * 32 + l15] = f2bf(a2[mi][0][reg]);
        ys[row16 * 32 + 16 + l15] = f2bf(a2[mi][1][reg]);
      }
    asm volatile("s_waitcnt lgkmcnt(0)" ::: "memory");
#pragma unroll
    for (int half = 0; half < 2; ++half) {
      int row = half * 16 + (lane >> 2);      // 0..31
      int chunk = lane & 3;                   // 16B chunk within 64B row slice
      uint4 v = *reinterpret_cast<const uint4*>(&ys[row * 32 + chunk * 8]);
      int grow = node0 + row;
      if (grow < N)
        *reinterpret_cast<uint4*>(Y2 + (size_t)grow * (REFF * 32) + rp * 32 + chunk * 8) = v;
    }
  }
}

// ---------------- layer 2 gather off CSR1: out[n] = bias2 + sum_r sum_e v*Y2[src][r] ----------------
__global__ __launch_bounds__(512, 8)
void gather_out_kernel(const EPair* __restrict__ pay1,
                       const int* __restrict__ ptr1,
                       const unsigned short* __restrict__ Y2,
                       const float* __restrict__ bias2,
                       float* __restrict__ out, int N) {
  int wv = threadIdx.x >> 6;
  int lane = threadIdx.x & 63;
  int qw = lane >> 4, c = lane & 15;
  int n = blockIdx.x * 8 + wv;
  if (n >= N) return;
  float ax = 0.f, ay = 0.f;
  for (int r = qw; r < REFF; r += 4) {
    int g = r * N + n;
    int p0 = ptr1[g], p1 = ptr1[g + 1];
    int p = p0;
    for (; p + 2 <= p1; p += 2) {
      EPair e0 = pay1[p];
      EPair e1 = pay1[p + 1];
      unsigned u0 = *reinterpret_cast<const unsigned*>(
          Y2 + (size_t)(e0.c & 0xFFFFF) * (REFF * 32) + r * 32 + c * 2);
      unsigned u1 = *reinterpret_cast<const unsigned*>(
          Y2 + (size_t)(e1.c & 0xFFFFF) * (REFF * 32) + r * 32 + c * 2);
      ax += e0.v * bflo(u0) + e1.v * bflo(u1);
      ay += e0.v * bfhi(u0) + e1.v * bfhi(u1);
    }
    if (p < p1) {
      EPair e0 = pay1[p];
      unsigned u0 = *reinterpret_cast<const unsigned*>(
          Y2 + (size_t)(e0.c & 0xFFFFF) * (REFF * 32) + r * 32 + c * 2);
      ax += e0.v * bflo(u0);
      ay += e0.v * bfhi(u0);
    }
  }
  ax += __shfl_xor(ax, 16); ay += __shfl_xor(ay, 16);
  ax += __shfl_xor(ax, 32); ay += __shfl_xor(ay, 32);
  if (lane < 16) {
    float2 o;
    o.x = ax + bias2[c * 2];
    o.y = ay + bias2[c * 2 + 1];
    reinterpret_cast<float2*>(out)[(size_t)n * 16 + c] = o;
  }
}

extern "C" void kernel_launch(void* const* d_in, const int* in_sizes, int n_in,
                              void* d_out, int out_size, void* d_ws, size_t ws_size,
                              hipStream_t stream) {
  const float* features = (const float*)d_in[0];
  const float* ver_vals = (const float*)d_in[1];
  const float* comps1   = (const float*)d_in[2];
  const float* bases1   = (const float*)d_in[3];
  const float* comps2   = (const float*)d_in[4];
  const float* bases2   = (const float*)d_in[5];
  const float* bias1    = (const float*)d_in[6];
  const float* bias2    = (const float*)d_in[7];
  const int* ver_rows   = (const int*)d_in[8];
  const int* ver_cols   = (const int*)d_in[9];

  const int N = in_sizes[0] / 256;   // 30000
  const int E = in_sizes[1];         // 500000
  const int NR = REFF * N;           // 270000
  const int NT = (NR + 1023) / 1024; // 264

  // ---- workspace layout (~40 MB; 64.1 MB proven-safe) ----
  char* p = (char*)d_ws;
  unsigned short* Xbf = (unsigned short*)p; p += (size_t)N * 256 * 2;        // 15.36 MB
  unsigned short* Y2  = (unsigned short*)p; p += (size_t)N * REFF * 32 * 2;  // 17.28 MB
  unsigned short* W1p = (unsigned short*)p; p += (size_t)REFF * 65536 * 2;   // 1.18 MB
  unsigned short* W2p = (unsigned short*)p; p += (size_t)REFF * 8192 * 2;    // 0.15 MB
  int* ptr1 = (int*)p;     p += (size_t)(NR + 4) * 4;
  EPair* pay1 = (EPair*)p; p += (size_t)E * 8;
  int* deg1 = (int*)p;     p += (size_t)NR * 4;
  int* bsum = (int*)p;     p += 512 * 4;

  // ---- CSR build + prep ----
  hipMemsetAsync(deg1, 0, (size_t)NR * 4, stream);
  const int prep_total = N * 64 + REFF * 8 * 16 * 512 + REFF * 8 * 2 * 512;
  const int hp_grid = ((prep_total > E ? prep_total : E) + 255) / 256;
  hist_prep_kernel<<<hp_grid, 256, 0, stream>>>(ver_rows, deg1, E,
                                                features, Xbf,
                                                comps1, bases1, W1p,
                                                comps2, bases2, W2p, N);
  scan1_kernel<<<NT, 256, 0, stream>>>(deg1, bsum, NR);
  scan2_kernel<<<1, 512, 0, stream>>>(bsum, ptr1, NT, NR);
  scan3_kernel<<<NT, 256, 0, stream>>>(deg1, bsum, ptr1, NR);
  fill_kernel<<<(E + 255) / 256, 256, 0, stream>>>(ver_rows, ver_cols, ver_vals,
                                                   deg1, ptr1, pay1, E, N);

  // ---- fused layer 1 (MFMA aggregation) + layer-2 transform ----
  fused_l1<<<(N + 31) / 32, 512, 0, stream>>>(pay1, ptr1, Xbf, W1p, bias1,
                                              W2p, Y2, N);
  // ---- layer 2 gather ----
  gather_out_kernel<<<(N + 7) / 8, 512, 0, stream>>>(pay1, ptr1, Y2, bias2,
                                                     (float*)d_out, N);
}

// Round 12
// 222.510 us; speedup vs baseline: 1.0936x; 1.0201x over previous
//
#include <hip/hip_runtime.h>

typedef __attribute__((ext_vector_type(8))) short bf16x8;
typedef __attribute__((ext_vector_type(4))) float f32x4;

constexpr int NB = 16;    // bases
constexpr int REFF = 9;   // relations

struct alignas(8) EPair { float v; int c; };   // c = src | (dst&31)<<20

__device__ __forceinline__ unsigned short f2bf(float f) {
  unsigned u = __float_as_uint(f);
  u += 0x7FFFu + ((u >> 16) & 1u);          // round-to-nearest-even
  return (unsigned short)(u >> 16);
}
__device__ __forceinline__ float bflo(unsigned u) {
  return __uint_as_float(u << 16);
}
__device__ __forceinline__ float bfhi(unsigned u) {
  return __uint_as_float(u & 0xFFFF0000u);
}

// ---------------- merged: histogram + prep (Xbf, W1p, W2p) ----------------
__device__ __forceinline__ unsigned short pack_w_one(const float* __restrict__ comps,
                                                     const float* __restrict__ bases,
                                                     int idx, int NTI, int NTOT) {
  int j = idx & 7;
  int lane = (idx >> 3) & 63;
  int ni = (idx >> 9) % NTI;
  int t = (idx >> 9) / NTI;        // r*8 + ks
  int ks = t & 7;
  int r = t >> 3;
  int k = ks * 32 + ((lane >> 4) << 3) + j;
  int n = ni * 16 + (lane & 15);
  float acc = 0.f;
#pragma unroll
  for (int b = 0; b < NB; ++b)
    acc += comps[r * NB + b] * bases[(size_t)b * 256 * NTOT + (size_t)k * NTOT + n];
  return f2bf(acc);
}

__global__ void hist_prep_kernel(const int* __restrict__ rows,
                                 int* __restrict__ deg1, int E,
                                 const float* __restrict__ features,
                                 unsigned short* __restrict__ Xbf,
                                 const float* __restrict__ comps1,
                                 const float* __restrict__ bases1,
                                 unsigned short* __restrict__ W1p,
                                 const float* __restrict__ comps2,
                                 const float* __restrict__ bases2,
                                 unsigned short* __restrict__ W2p, int N) {
  int idx = blockIdx.x * 256 + threadIdx.x;
  if (idx < E) atomicAdd(&deg1[rows[idx]], 1);
  const int n4 = N * 64;                 // float4 units of features
  const int PW1 = REFF * 8 * 16 * 512;   // 589824
  const int PW2 = REFF * 8 * 2 * 512;    // 73728
  if (idx < n4) {
    float4 f = reinterpret_cast<const float4*>(features)[idx];
    ushort4 o;
    o.x = f2bf(f.x); o.y = f2bf(f.y); o.z = f2bf(f.z); o.w = f2bf(f.w);
    reinterpret_cast<ushort4*>(Xbf)[idx] = o;
  } else if (idx < n4 + PW1) {
    int i = idx - n4;
    W1p[i] = pack_w_one(comps1, bases1, i, 16, 256);
  } else if (idx < n4 + PW1 + PW2) {
    int i = idx - n4 - PW1;
    W2p[i] = pack_w_one(comps2, bases2, i, 2, 32);
  }
}

// ---------------- scan over NR rows (R3-proven 3-pass) ----------------
__global__ void scan1_kernel(const int* __restrict__ deg, int* __restrict__ bsum,
                             int NR) {
  __shared__ int s[256];
  int t = threadIdx.x;
  int base = blockIdx.x * 1024 + t * 4;
  int acc = 0;
#pragma unroll
  for (int q = 0; q < 4; ++q)
    if (base + q < NR) acc += deg[base + q];
  s[t] = acc;
  __syncthreads();
  for (int off = 128; off > 0; off >>= 1) {
    if (t < off) s[t] += s[t + off];
    __syncthreads();
  }
  if (t == 0) bsum[blockIdx.x] = s[0];
}

__global__ void scan2_kernel(int* __restrict__ bsum, int* __restrict__ ptr,
                             int NT, int NR) {
  __shared__ int s[512];
  int t = threadIdx.x;
  int v = (t < NT) ? bsum[t] : 0;
  s[t] = v;
  __syncthreads();
  for (int off = 1; off < 512; off <<= 1) {
    int x = (t >= off) ? s[t - off] : 0;
    __syncthreads();
    s[t] += x;
    __syncthreads();
  }
  if (t < NT) bsum[t] = s[t] - v;          // exclusive
  if (t == NT - 1) ptr[NR] = s[t];
}

__global__ void scan3_kernel(const int* __restrict__ deg,
                             const int* __restrict__ bsum,
                             int* __restrict__ ptr, int NR) {
  __shared__ int s[256];
  int t = threadIdx.x;
  int base = blockIdx.x * 1024 + t * 4;
  int d[4];
#pragma unroll
  for (int q = 0; q < 4; ++q)
    d[q] = (base + q < NR) ? deg[base + q] : 0;
  int tsum = d[0] + d[1] + d[2] + d[3];
  s[t] = tsum;
  __syncthreads();
  for (int off = 1; off < 256; off <<= 1) {
    int x = (t >= off) ? s[t - off] : 0;
    __syncthreads();
    s[t] += x;
    __syncthreads();
  }
  int off0 = bsum[blockIdx.x] + s[t] - tsum;
#pragma unroll
  for (int q = 0; q < 4; ++q) {
    if (base + q < NR) ptr[base + q] = off0;
    off0 += d[q];
  }
}

__global__ void fill_kernel(const int* __restrict__ rows,
                            const int* __restrict__ cols,
                            const float* __restrict__ vals,
                            int* __restrict__ deg1, const int* __restrict__ ptr1,
                            EPair* __restrict__ pay1, int E, int N) {
  int e = blockIdx.x * 256 + threadIdx.x;
  if (e >= E) return;
  int g = rows[e];
  int dst = g % N;
  int o1 = atomicSub(&deg1[g], 1);
  EPair pv; pv.v = vals[e]; pv.c = cols[e] | ((dst & 31) << 20);
  pay1[ptr1[g] + o1 - 1] = pv;
}

// ---------------- fused layer 1 (MFMA-aggregation, pipelined) + layer-2 transform ----------------
// 512 threads / 8 waves; 32-node tile. Per relation: edges in chunks of 32;
// stage Xt[256 n][32 k] transposed + Mt[32 node][32 k] coeffs; aggT = Xt @ Mt via MFMA.
// Chunk c+1's global loads are issued before chunk c's MFMA (T14 async-stage split).
__global__ __launch_bounds__(512, 4)
void fused_l1(const EPair* __restrict__ pay1, const int* __restrict__ ptr1,
              const unsigned short* __restrict__ Xbf,
              const unsigned short* __restrict__ W1p,
              const float* __restrict__ bias1,
              const unsigned short* __restrict__ W2p,
              unsigned short* __restrict__ Y2, int N) {
  __shared__ char smem[34 * 1024];
  char* Xt   = smem;               // 16 KB: [256 n][32 k] bf16, k-groups swizzled
  char* Mt   = smem + 16 * 1024;   // 2 KB:  [32 node][32 k] bf16, swizzled
  char* tile = smem + 18 * 1024;   // 16 KB: [32 node][256 n] bf16 (W1 A-tile layout)
  const int tid = threadIdx.x;
  const int w = tid >> 6, lane = tid & 63;
  const int l15 = lane & 15, kg = lane >> 4;
  const int node0 = blockIdx.x * 32;
  const int nrows = (N - node0 < 32) ? (N - node0) : 32;

  // zero Xt once (stale finite data is fine later; initial LDS may be NaN-patterned)
  {
    uint4 z = make_uint4(0, 0, 0, 0);
    *reinterpret_cast<uint4*>(Xt + tid * 32) = z;
    *reinterpret_cast<uint4*>(Xt + tid * 32 + 16) = z;
  }
  __syncthreads();

  f32x4 acc[2][2];
#pragma unroll
  for (int mi = 0; mi < 2; ++mi)
#pragma unroll
    for (int ni = 0; ni < 2; ++ni) acc[mi][ni] = (f32x4)(0.f);

  // staging coords: thread t handles edge slot k = t&31, n-range [(t>>5)*16, +16)
  const int sk = tid & 31;
  const int sn0 = (tid >> 5) << 4;

  for (int r = 0; r < REFF; ++r) {
    int g = r * N + node0;
    int s0 = ptr1[g], s1 = ptr1[g + nrows];
    int nch = (s1 - s0 + 31) >> 5;

    f32x4 agg[2][2];
#pragma unroll
    for (int mi = 0; mi < 2; ++mi)
#pragma unroll
      for (int ni = 0; ni < 2; ++ni) agg[mi][ni] = (f32x4)(0.f);

    // prologue: fetch chunk 0 into registers
    EPair pe; bf16x8 px0, px1;
    {
      int rem = s1 - s0; if (rem > 32) rem = 32;
      if (sk < rem) {
        pe = pay1[s0 + sk];
        const unsigned short* xr = Xbf + (size_t)(pe.c & 0xFFFFF) * 256 + sn0;
        px0 = *reinterpret_cast<const bf16x8*>(xr);
        px1 = *reinterpret_cast<const bf16x8*>(xr + 8);
      }
    }

    for (int c = 0; c < nch; ++c) {
      int e0 = s0 + c * 32;
      int rem = s1 - e0; if (rem > 32) rem = 32;
      // ---- write phase: publish chunk c from registers ----
      if (sk < rem) {
        int klo = sk & 7;
        int kgr = sk >> 3;
#pragma unroll
        for (int i = 0; i < 8; ++i) {
          int n = sn0 + i;
          int off = n * 64 + (((kgr ^ (n & 3)) << 3 | klo) << 1);
          *reinterpret_cast<unsigned short*>(Xt + off) = (unsigned short)px0[i];
        }
#pragma unroll
        for (int i = 0; i < 8; ++i) {
          int n = sn0 + 8 + i;
          int off = n * 64 + (((kgr ^ (n & 3)) << 3 | klo) << 1);
          *reinterpret_cast<unsigned short*>(Xt + off) = (unsigned short)px1[i];
        }
      }
      // Mt: wave 0 zeros then populates from its own prefetch regs (lanes 0..31
      // hold exactly edges e0..e0+31; same-wave LDS ops are ordered)
      if (tid < 64) {
        uint4 z = make_uint4(0, 0, 0, 0);
        *reinterpret_cast<uint4*>(Mt + tid * 32) = z;
        *reinterpret_cast<uint4*>(Mt + tid * 32 + 16) = z;
      }
      if (tid < 32 && sk < rem) {
        int rr = (pe.c >> 20) & 31;
        int off = rr * 64 + (((((sk >> 3) ^ (rr & 3)) << 3) | (sk & 7)) << 1);
        *reinterpret_cast<unsigned short*>(Mt + off) = f2bf(pe.v);
      }
      __syncthreads();
      // ---- issue chunk c+1 loads (latency hides under MFMA + barrier + next writes) ----
      if (c + 1 < nch) {
        int e0n = e0 + 32;
        int remn = s1 - e0n; if (remn > 32) remn = 32;
        if (sk < remn) {
          pe = pay1[e0n + sk];
          const unsigned short* xr = Xbf + (size_t)(pe.c & 0xFFFFF) * 256 + sn0;
          px0 = *reinterpret_cast<const bf16x8*>(xr);
          px1 = *reinterpret_cast<const bf16x8*>(xr + 8);
        }
      }
      // ---- aggT += Xt(32n-slice) @ Mt ----
      {
        int n_0 = w * 32 + l15;
        int n_1 = n_0 + 16;
        bf16x8 a0 = *reinterpret_cast<const bf16x8*>(
            Xt + n_0 * 64 + ((kg ^ (n_0 & 3)) << 4));
        bf16x8 a1 = *reinterpret_cast<const bf16x8*>(
            Xt + n_1 * 64 + ((kg ^ (n_1 & 3)) << 4));
        bf16x8 b0 = *reinterpret_cast<const bf16x8*>(
            Mt + l15 * 64 + ((kg ^ (l15 & 3)) << 4));
        bf16x8 b1 = *reinterpret_cast<const bf16x8*>(
            Mt + (l15 + 16) * 64 + ((kg ^ (l15 & 3)) << 4));
        agg[0][0] = __builtin_amdgcn_mfma_f32_16x16x32_bf16(a0, b0, agg[0][0], 0, 0, 0);
        agg[0][1] = __builtin_amdgcn_mfma_f32_16x16x32_bf16(a0, b1, agg[0][1], 0, 0, 0);
        agg[1][0] = __builtin_amdgcn_mfma_f32_16x16x32_bf16(a1, b0, agg[1][0], 0, 0, 0);
        agg[1][1] = __builtin_amdgcn_mfma_f32_16x16x32_bf16(a1, b1, agg[1][1], 0, 0, 0);
      }
      __syncthreads();
    }

    // ---- write aggT -> tile[node][n] (bf16, swizzled W1 A-layout) ----
#pragma unroll
    for (int mi = 0; mi < 2; ++mi)
#pragma unroll
      for (int ni = 0; ni < 2; ++ni)
#pragma unroll
        for (int reg = 0; reg < 4; ++reg) {
          int node = ni * 16 + l15;
          int n = w * 32 + mi * 16 + kg * 4 + reg;
          int byte = (node * 512 + n * 2) ^ ((node & 7) << 4);
          *reinterpret_cast<unsigned short*>(tile + byte) = f2bf(agg[mi][ni][reg]);
        }
    __syncthreads();
    // ---- acc += tile @ W1_r ----
#pragma unroll 2
    for (int ks = 0; ks < 8; ++ks) {
      bf16x8 a[2];
#pragma unroll
      for (int mi = 0; mi < 2; ++mi) {
        int row = mi * 16 + l15;
        int boff = (row * 512 + ks * 64 + (kg << 4)) ^ ((row & 7) << 4);
        a[mi] = *reinterpret_cast<const bf16x8*>(tile + boff);
      }
#pragma unroll
      for (int ni = 0; ni < 2; ++ni) {
        int niG = w * 2 + ni;
        bf16x8 b = *reinterpret_cast<const bf16x8*>(
            W1p + (((size_t)(r * 8 + ks) * 16 + niG) << 9) + lane * 8);
#pragma unroll
        for (int mi = 0; mi < 2; ++mi)
          acc[mi][ni] = __builtin_amdgcn_mfma_f32_16x16x32_bf16(a[mi], b,
                                                               acc[mi][ni], 0, 0, 0);
      }
    }
    __syncthreads();
  }

  // epilogue: out1 tile = bf16(relu(acc + bias1)) -> tile (same layout)
#pragma unroll
  for (int mi = 0; mi < 2; ++mi) {
#pragma unroll
    for (int ni = 0; ni < 2; ++ni) {
      int col = (w * 2 + ni) * 16 + l15;
      float bb = bias1[col];
#pragma unroll
      for (int reg = 0; reg < 4; ++reg) {
        int row = mi * 16 + (kg << 2) + reg;
        float v = fmaxf(acc[mi][ni][reg] + bb, 0.f);
        int b = (row * 512 + col * 2) ^ ((row & 7) << 4);
        *reinterpret_cast<unsigned short*>(tile + b) = f2bf(v);
      }
    }
  }
  __syncthreads();

  // layer-2 transform: wave w handles rp = w (wave 0 also rp=8); staged stores
  unsigned short* ys = reinterpret_cast<unsigned short*>(Xt) + w * 1024;  // 2 KB/wave
  for (int rp = w; rp < REFF; rp += 8) {
    f32x4 a2[2][2];   // [mi][nj]
#pragma unroll
    for (int mi = 0; mi < 2; ++mi) {
      a2[mi][0] = (f32x4)(0.f);
      a2[mi][1] = (f32x4)(0.f);
    }
#pragma unroll
    for (int ks = 0; ks < 8; ++ks) {
      bf16x8 b0 = *reinterpret_cast<const bf16x8*>(
          W2p + (((size_t)(rp * 8 + ks) * 2 + 0) << 9) + lane * 8);
      bf16x8 b1 = *reinterpret_cast<const bf16x8*>(
          W2p + (((size_t)(rp * 8 + ks) * 2 + 1) << 9) + lane * 8);
#pragma unroll
      for (int mi = 0; mi < 2; ++mi) {
        int row = mi * 16 + l15;
        int boff = (row * 512 + ks * 64 + (kg << 4)) ^ ((row & 7) << 4);
        bf16x8 a = *reinterpret_cast<const bf16x8*>(tile + boff);
        a2[mi][0] = __builtin_amdgcn_mfma_f32_16x16x32_bf16(a, b0, a2[mi][0], 0, 0, 0);
        a2[mi][1] = __builtin_amdgcn_mfma_f32_16x16x32_bf16(a, b1, a2[mi][1], 0, 0, 0);
      }
    }
    // stage 32x32 bf16 into wave-private LDS, then full-line stores
#pragma unroll
    for (int mi = 0; mi < 2; ++mi)
#pragma unroll
      for (int reg = 0; reg < 4; ++reg) {
        int row16 = mi * 16 + (kg << 2) + reg;
        ys[row16 * 32 + l15] = f2bf(a2[mi][0][reg]);
        ys[row16 * 32 + 16 + l15] = f2bf(a2[mi][1][reg]);
      }
    asm volatile("s_waitcnt lgkmcnt(0)" ::: "memory");
#pragma unroll
    for (int half = 0; half < 2; ++half) {
      int row = half * 16 + (lane >> 2);      // 0..31
      int chunk = lane & 3;                   // 16B chunk within 64B row slice
      uint4 v = *reinterpret_cast<const uint4*>(&ys[row * 32 + chunk * 8]);
      int grow = node0 + row;
      if (grow < N)
        *reinterpret_cast<uint4*>(Y2 + (size_t)grow * (REFF * 32) + rp * 32 + chunk * 8) = v;
    }
  }
}

// ---------------- layer 2 gather off CSR1: out[n] = bias2 + sum_r sum_e v*Y2[src][r] ----------------
__global__ __launch_bounds__(512, 8)
void gather_out_kernel(const EPair* __restrict__ pay1,
                       const int* __restrict__ ptr1,
                       const unsigned short* __restrict__ Y2,
                       const float* __restrict__ bias2,
                       float* __restrict__ out, int N) {
  int wv = threadIdx.x >> 6;
  int lane = threadIdx.x & 63;
  int qw = lane >> 4, c = lane & 15;
  int n = blockIdx.x * 8 + wv;
  if (n >= N) return;
  float ax = 0.f, ay = 0.f;
  for (int r = qw; r < REFF; r += 4) {
    int g = r * N + n;
    int p0 = ptr1[g], p1 = ptr1[g + 1];
    int p = p0;
    for (; p + 2 <= p1; p += 2) {
      EPair e0 = pay1[p];
      EPair e1 = pay1[p + 1];
      unsigned u0 = *reinterpret_cast<const unsigned*>(
          Y2 + (size_t)(e0.c & 0xFFFFF) * (REFF * 32) + r * 32 + c * 2);
      unsigned u1 = *reinterpret_cast<const unsigned*>(
          Y2 + (size_t)(e1.c & 0xFFFFF) * (REFF * 32) + r * 32 + c * 2);
      ax += e0.v * bflo(u0) + e1.v * bflo(u1);
      ay += e0.v * bfhi(u0) + e1.v * bfhi(u1);
    }
    if (p < p1) {
      EPair e0 = pay1[p];
      unsigned u0 = *reinterpret_cast<const unsigned*>(
          Y2 + (size_t)(e0.c & 0xFFFFF) * (REFF * 32) + r * 32 + c * 2);
      ax += e0.v * bflo(u0);
      ay += e0.v * bfhi(u0);
    }
  }
  ax += __shfl_xor(ax, 16); ay += __shfl_xor(ay, 16);
  ax += __shfl_xor(ax, 32); ay += __shfl_xor(ay, 32);
  if (lane < 16) {
    float2 o;
    o.x = ax + bias2[c * 2];
    o.y = ay + bias2[c * 2 + 1];
    reinterpret_cast<float2*>(out)[(size_t)n * 16 + c] = o;
  }
}

extern "C" void kernel_launch(void* const* d_in, const int* in_sizes, int n_in,
                              void* d_out, int out_size, void* d_ws, size_t ws_size,
                              hipStream_t stream) {
  const float* features = (const float*)d_in[0];
  const float* ver_vals = (const float*)d_in[1];
  const float* comps1   = (const float*)d_in[2];
  const float* bases1   = (const float*)d_in[3];
  const float* comps2   = (const float*)d_in[4];
  const float* bases2   = (const float*)d_in[5];
  const float* bias1    = (const float*)d_in[6];
  const float* bias2    = (const float*)d_in[7];
  const int* ver_rows   = (const int*)d_in[8];
  const int* ver_cols   = (const int*)d_in[9];

  const int N = in_sizes[0] / 256;   // 30000
  const int E = in_sizes[1];         // 500000
  const int NR = REFF * N;           // 270000
  const int NT = (NR + 1023) / 1024; // 264

  // ---- workspace layout (~40 MB; 64.1 MB proven-safe) ----
  char* p = (char*)d_ws;
  unsigned short* Xbf = (unsigned short*)p; p += (size_t)N * 256 * 2;        // 15.36 MB
  unsigned short* Y2  = (unsigned short*)p; p += (size_t)N * REFF * 32 * 2;  // 17.28 MB
  unsigned short* W1p = (unsigned short*)p; p += (size_t)REFF * 65536 * 2;   // 1.18 MB
  unsigned short* W2p = (unsigned short*)p; p += (size_t)REFF * 8192 * 2;    // 0.15 MB
  int* ptr1 = (int*)p;     p += (size_t)(NR + 4) * 4;
  EPair* pay1 = (EPair*)p; p += (size_t)E * 8;
  int* deg1 = (int*)p;     p += (size_t)NR * 4;
  int* bsum = (int*)p;     p += 512 * 4;

  // ---- CSR build + prep ----
  hipMemsetAsync(deg1, 0, (size_t)NR * 4, stream);
  const int prep_total = N * 64 + REFF * 8 * 16 * 512 + REFF * 8 * 2 * 512;
  const int hp_grid = ((prep_total > E ? prep_total : E) + 255) / 256;
  hist_prep_kernel<<<hp_grid, 256, 0, stream>>>(ver_rows, deg1, E,
                                                features, Xbf,
                                                comps1, bases1, W1p,
                                                comps2, bases2, W2p, N);
  scan1_kernel<<<NT, 256, 0, stream>>>(deg1, bsum, NR);
  scan2_kernel<<<1, 512, 0, stream>>>(bsum, ptr1, NT, NR);
  scan3_kernel<<<NT, 256, 0, stream>>>(deg1, bsum, ptr1, NR);
  fill_kernel<<<(E + 255) / 256, 256, 0, stream>>>(ver_rows, ver_cols, ver_vals,
                                                   deg1, ptr1, pay1, E, N);

  // ---- fused layer 1 (MFMA aggregation, pipelined) + layer-2 transform ----
  fused_l1<<<(N + 31) / 32, 512, 0, stream>>>(pay1, ptr1, Xbf, W1p, bias1,
                                              W2p, Y2, N);
  // ---- layer 2 gather ----
  gather_out_kernel<<<(N + 7) / 8, 512, 0, stream>>>(pay1, ptr1, Y2, bias2,
                                                     (float*)d_out, N);
}